// Round 1
// baseline (218.026 us; speedup 1.0000x reference)
//
#include <hip/hip_runtime.h>
#include <math.h>

#define NN 96
#define DD 512
#define PP 9120   // NN*(NN-1)
#define EPSF 1e-8f
#define INV_TEMP 100.0f

// p -> ordered pair (i, j), i != j, row-major over the i!=j mask
__device__ __forceinline__ void decomp(unsigned p, int& i, int& j) {
    unsigned ii = p / 95u;          // const-divisor magic-mul
    unsigned r  = p - ii * 95u;
    i = (int)ii;
    j = (int)(r + (r >= ii ? 1u : 0u));
}

// ws layout (floats): [0:4*9216) = G, GT, Gt, Gm ; then inv_nt[P], inv_nm[P], diag[P], lse[2P]

// z=0: G = txt*img^T ; z=1: GT = img*txt^T ; z=2: Gt = txt*txt^T ; z=3: Gm = img*img^T
__global__ void gram_kernel(const float* __restrict__ txt,
                            const float* __restrict__ img,
                            float* __restrict__ ws) {
    int a = blockIdx.x, b = blockIdx.y, z = blockIdx.z;
    const float* X = (z == 1 || z == 3) ? img : txt;
    const float* Y = (z == 0 || z == 3) ? img : txt;
    int lane = threadIdx.x;
    const float* xr = X + a * DD;
    const float* yr = Y + b * DD;
    float acc = 0.f;
    #pragma unroll
    for (int it = 0; it < DD / 64; ++it) {
        int d = lane + it * 64;
        acc += xr[d] * yr[d];
    }
    #pragma unroll
    for (int off = 32; off > 0; off >>= 1)
        acc += __shfl_down(acc, off, 64);
    if (lane == 0) ws[z * (NN * NN) + a * NN + b] = acc;
}

__global__ void pairs_kernel(const float* __restrict__ ws_g,
                             float* __restrict__ inv_nt,
                             float* __restrict__ inv_nm,
                             float* __restrict__ diag) {
    int p = blockIdx.x * blockDim.x + threadIdx.x;
    if (p >= PP) return;
    int i, j; decomp((unsigned)p, i, j);
    const float* G  = ws_g;
    const float* Gt = ws_g + 2 * NN * NN;
    const float* Gm = ws_g + 3 * NN * NN;
    float nt2 = Gt[i * NN + i] - 2.f * Gt[i * NN + j] + Gt[j * NN + j];
    float nm2 = Gm[i * NN + i] - 2.f * Gm[i * NN + j] + Gm[j * NN + j];
    float rt = 1.f / (sqrtf(fmaxf(nt2, 0.f)) + EPSF);
    float rm = 1.f / (sqrtf(fmaxf(nm2, 0.f)) + EPSF);
    inv_nt[p] = rt;
    inv_nm[p] = rm;
    float dv = G[i * NN + i] - G[i * NN + j] - G[j * NN + i] + G[j * NN + j];
    diag[p] = INV_TEMP * rt * rm * dv;
}

// One block per LSE task. Tasks [0,P): row p of mma. Tasks [P,2P): col q of mma.
// Row p=(i,j):  v_u = 100*inv_nt[p] * inv_nm[u] * (A[k]-A[l]),  A[x] = G[i,x]-G[j,x],  u=(k,l)
// Col q=(k,l):  v_u = 100*inv_nm[q] * inv_nt[u] * (B[x_i]-B[x_j]), B[x] = GT[k,x]-GT[l,x]
__global__ __launch_bounds__(256) void lse_kernel(const float* __restrict__ ws_g,
                                                  const float* __restrict__ inv_nt,
                                                  const float* __restrict__ inv_nm,
                                                  float* __restrict__ lse) {
    __shared__ float vals[PP];
    __shared__ float avec[NN];
    __shared__ float red[256];
    int b = blockIdx.x;
    int tid = threadIdx.x;
    bool is_col = (b >= PP);
    int p = is_col ? b - PP : b;
    int i, j; decomp((unsigned)p, i, j);
    const float* M = is_col ? (ws_g + NN * NN) : ws_g;     // GT for col tasks, G for row tasks
    const float* invOther = is_col ? inv_nt : inv_nm;
    float s = INV_TEMP * (is_col ? inv_nm[p] : inv_nt[p]);
    for (int x = tid; x < NN; x += 256)
        avec[x] = s * (M[i * NN + x] - M[j * NN + x]);
    __syncthreads();

    float lmax = -INFINITY;
    for (int u = tid; u < PP; u += 256) {
        int k, l; decomp((unsigned)u, k, l);
        float v = invOther[u] * (avec[k] - avec[l]);
        vals[u] = v;
        lmax = fmaxf(lmax, v);
    }
    red[tid] = lmax; __syncthreads();
    for (int t = 128; t > 0; t >>= 1) {
        if (tid < t) red[tid] = fmaxf(red[tid], red[tid + t]);
        __syncthreads();
    }
    float m = red[0];
    __syncthreads();

    float lsum = 0.f;
    for (int u = tid; u < PP; u += 256)
        lsum += __expf(vals[u] - m);
    red[tid] = lsum; __syncthreads();
    for (int t = 128; t > 0; t >>= 1) {
        if (tid < t) red[tid] += red[tid + t];
        __syncthreads();
    }
    if (tid == 0) lse[b] = m + logf(red[0]);
}

__global__ void final_kernel(const float* __restrict__ lse,
                             const float* __restrict__ diag,
                             float* __restrict__ out) {
    __shared__ float red[256];
    int tid = threadIdx.x;
    float s = 0.f;
    for (int p = tid; p < PP; p += 256)
        s += (lse[p] - diag[p]) + (lse[PP + p] - diag[p]);
    red[tid] = s; __syncthreads();
    for (int t = 128; t > 0; t >>= 1) {
        if (tid < t) red[tid] += red[tid + t];
        __syncthreads();
    }
    if (tid == 0) out[0] = red[0] / (2.0f * PP);
}

extern "C" void kernel_launch(void* const* d_in, const int* in_sizes, int n_in,
                              void* d_out, int out_size, void* d_ws, size_t ws_size,
                              hipStream_t stream) {
    const float* txt = (const float*)d_in[0];
    const float* img = (const float*)d_in[1];
    float* ws = (float*)d_ws;
    float* inv_nt = ws + 4 * NN * NN;
    float* inv_nm = inv_nt + PP;
    float* diag   = inv_nm + PP;
    float* lse    = diag + PP;

    gram_kernel<<<dim3(NN, NN, 4), 64, 0, stream>>>(txt, img, ws);
    pairs_kernel<<<(PP + 255) / 256, 256, 0, stream>>>(ws, inv_nt, inv_nm, diag);
    lse_kernel<<<2 * PP, 256, 0, stream>>>(ws, inv_nt, inv_nm, lse);
    final_kernel<<<1, 256, 0, stream>>>(lse, diag, (float*)d_out);
}

// Round 2
// 140.242 us; speedup vs baseline: 1.5546x; 1.5546x over previous
//
#include <hip/hip_runtime.h>
#include <math.h>

#define NN 96
#define DD 512
#define PP 9120          // NN*(NN-1)
#define EPSF 1e-8f
#define INV_TEMP 100.0f
#define LOG2E 1.4426950408889634f
#define RT 4             // tasks (rows/cols of mma) per block
#define NTASK (2*PP)     // 18240
#define NBLK (NTASK/RT)  // 4560
#define CBASE (PP/RT)    // 2280: first block index handling column tasks

// ws float-offset layout
#define OFF_G     0        // G  = txt*img^T   [96*96]
#define OFF_GT    9216     // GT = img*txt^T   [96*96]
#define OFF_GTT   18432    // Gt = txt*txt^T   [96*96]
#define OFF_GMM   27648    // Gm = img*img^T   [96*96]
#define OFF_WT    36864    // wt[k][l] = 1/(||t_k-t_l||+eps), diag 0
#define OFF_WM    46080    // wm grid
#define OFF_WST   55296    // wt * log2e
#define OFF_WSM   64512    // wm * log2e
#define OFF_DIAG  73728    // diag[p], p in [0,9120)
#define OFF_WMAX  82848    // [0]=max wt, [1]=max wm (as uint bits)

__device__ __forceinline__ void decomp(unsigned p, int& i, int& j) {
    unsigned ii = p / 95u;
    unsigned r  = p - ii * 95u;
    i = (int)ii;
    j = (int)(r + (r >= ii ? 1u : 0u));
}

// one wave per gram element; z=0:G z=1:GT z=2:Gt z=3:Gm
__global__ void gram_kernel(const float* __restrict__ txt,
                            const float* __restrict__ img,
                            float* __restrict__ ws) {
    int a = blockIdx.x, b = blockIdx.y, z = blockIdx.z;
    const float* X = (z == 1 || z == 3) ? img : txt;
    const float* Y = (z == 0 || z == 3) ? img : txt;
    int lane = threadIdx.x;
    const float4* xr = (const float4*)(X + a * DD);
    const float4* yr = (const float4*)(Y + b * DD);
    float4 x0 = xr[lane], x1 = xr[lane + 64];
    float4 y0 = yr[lane], y1 = yr[lane + 64];
    float acc = x0.x*y0.x + x0.y*y0.y + x0.z*y0.z + x0.w*y0.w
              + x1.x*y1.x + x1.y*y1.y + x1.z*y1.z + x1.w*y1.w;
    #pragma unroll
    for (int off = 32; off > 0; off >>= 1)
        acc += __shfl_xor(acc, off, 64);
    if (lane == 0) ws[z * (NN * NN) + a * NN + b] = acc;
}

// per (k,l) grid point: inverse-norm grids (+log2e-scaled copies), diag values, Wmax
__global__ void pairs_kernel(float* __restrict__ ws) {
    int t = blockIdx.x * 256 + threadIdx.x;
    if (t >= NN * NN) return;
    int k = t / NN, l = t - k * NN;
    const float* G  = ws + OFF_G;
    const float* Gt = ws + OFF_GTT;
    const float* Gm = ws + OFF_GMM;
    float wtv = 0.f, wmv = 0.f;
    if (k != l) {
        float nt2 = Gt[k*NN+k] - 2.f*Gt[k*NN+l] + Gt[l*NN+l];
        float nm2 = Gm[k*NN+k] - 2.f*Gm[k*NN+l] + Gm[l*NN+l];
        wtv = 1.f / (sqrtf(fmaxf(nt2, 0.f)) + EPSF);
        wmv = 1.f / (sqrtf(fmaxf(nm2, 0.f)) + EPSF);
        atomicMax((unsigned int*)(ws + OFF_WMAX) + 0, __float_as_uint(wtv));
        atomicMax((unsigned int*)(ws + OFF_WMAX) + 1, __float_as_uint(wmv));
        int p = k * 95 + l - (l > k ? 1 : 0);
        float dv = G[k*NN+k] - G[k*NN+l] - G[l*NN+k] + G[l*NN+l];
        ws[OFF_DIAG + p] = INV_TEMP * wtv * wmv * dv;
    }
    ws[OFF_WT  + t] = wtv;
    ws[OFF_WM  + t] = wmv;
    ws[OFF_WST + t] = wtv * LOG2E;
    ws[OFF_WSM + t] = wmv * LOG2E;
}

// One block = RT consecutive tasks (all-row or all-col). Sweep the full 96x96
// (k,l) grid (diag has w=0 -> contributes exp(-M) each, subtracted exactly).
// Shift M_r = Wmax * (amax_r - amin_r) >= true row max: exact LSE, no max pass.
__global__ __launch_bounds__(256) void lse_kernel(const float* __restrict__ ws,
                                                  float* __restrict__ out) {
    __shared__ float A[RT * NN];
    __shared__ float M2s[RT];     // M * log2e
    __shared__ float Ms[RT];      // M
    __shared__ float wred[4][RT];
    __shared__ float cred[RT];

    int tid = threadIdx.x, lane = tid & 63, wv = tid >> 6;
    int b = blockIdx.x;
    bool is_col = (b >= CBASE);
    const float* Mat    = ws + (is_col ? OFF_GT  : OFF_G);
    const float* wself  = ws + (is_col ? OFF_WM  : OFF_WT);
    const float* wsweep = ws + (is_col ? OFF_WST : OFF_WSM);
    float Wmax = __uint_as_float(((const unsigned int*)(ws + OFF_WMAX))[is_col ? 0 : 1]);
    int base = (b - (is_col ? CBASE : 0)) * RT;

    // wave wv builds row wv of A
    {
        int i, j; decomp((unsigned)(base + wv), i, j);
        float s = INV_TEMP * wself[i * NN + j];
        const float* Mi = Mat + i * NN;
        const float* Mj = Mat + j * NN;
        float v0 = s * (Mi[lane] - Mj[lane]);
        A[wv * NN + lane] = v0;
        float vmax = v0, vmin = v0;
        if (lane < 32) {
            float v1 = s * (Mi[64 + lane] - Mj[64 + lane]);
            A[wv * NN + 64 + lane] = v1;
            vmax = fmaxf(vmax, v1); vmin = fminf(vmin, v1);
        }
        #pragma unroll
        for (int off = 32; off > 0; off >>= 1) {
            vmax = fmaxf(vmax, __shfl_xor(vmax, off, 64));
            vmin = fminf(vmin, __shfl_xor(vmin, off, 64));
        }
        if (lane == 0) {
            float M = Wmax * (vmax - vmin);   // >= 0, >= all v in this row
            Ms[wv] = M;
            M2s[wv] = M * LOG2E;
        }
    }
    __syncthreads();

    int l1 = (lane < 32) ? (64 + lane) : (lane - 32);
    float M2[RT], aL0[RT], aL1[RT], aL2[RT], S[RT];
    #pragma unroll
    for (int r = 0; r < RT; ++r) {
        M2[r] = M2s[r];
        aL0[r] = A[r * NN + lane];
        aL1[r] = A[r * NN + l1];
        aL2[r] = A[r * NN + lane + 32];
        S[r] = 0.f;
    }

    // wave wv handles k-pairs {wv, wv+4, ...}: (k0,k1)=(2idx,2idx+1)
    // 3 steps cover (2 k) x (96 l) = 192 elements with 64 lanes, no padding:
    //  step0: (k0, lane)   step1: lane<32 ? (k0,64+lane) : (k1,lane-32)   step2: (k1, 32+lane)
    for (int idx = wv; idx < 48; idx += 4) {
        int k0 = 2 * idx, k1 = k0 + 1;
        float w0 = wsweep[k0 * NN + lane];
        float w1 = wsweep[(lane < 32 ? k0 : k1) * NN + l1];
        float w2 = wsweep[k1 * NN + lane + 32];
        #pragma unroll
        for (int r = 0; r < RT; ++r) {
            float2 ak = *(const float2*)&A[r * NN + k0];   // k0 even -> 8B aligned
            float aksel = (lane < 32) ? ak.x : ak.y;
            S[r] += __builtin_amdgcn_exp2f(w0 * (ak.x  - aL0[r]) - M2[r])
                  + __builtin_amdgcn_exp2f(w1 * (aksel - aL1[r]) - M2[r])
                  + __builtin_amdgcn_exp2f(w2 * (ak.y  - aL2[r]) - M2[r]);
        }
    }

    // reduce S across lanes then waves
    #pragma unroll
    for (int off = 32; off > 0; off >>= 1) {
        #pragma unroll
        for (int r = 0; r < RT; ++r) S[r] += __shfl_xor(S[r], off, 64);
    }
    if (lane == 0) {
        #pragma unroll
        for (int r = 0; r < RT; ++r) wred[wv][r] = S[r];
    }
    __syncthreads();

    if (tid < RT) {
        int r = tid;
        float tot = wred[0][r] + wred[1][r] + wred[2][r] + wred[3][r];
        tot -= 96.f * __builtin_amdgcn_exp2f(-M2s[r]);     // remove w=0 diagonal terms
        float lse = Ms[r] + logf(tot);
        cred[r] = lse - ws[OFF_DIAG + base + r];
    }
    __syncthreads();
    if (tid == 0) {
        float c = cred[0] + cred[1] + cred[2] + cred[3];
        atomicAdd(out, c * (1.0f / (float)NTASK));
    }
}

extern "C" void kernel_launch(void* const* d_in, const int* in_sizes, int n_in,
                              void* d_out, int out_size, void* d_ws, size_t ws_size,
                              hipStream_t stream) {
    const float* txt = (const float*)d_in[0];
    const float* img = (const float*)d_in[1];
    float* ws = (float*)d_ws;

    hipMemsetAsync(ws + OFF_WMAX, 0, 2 * sizeof(float), stream);
    hipMemsetAsync(d_out, 0, sizeof(float), stream);
    gram_kernel<<<dim3(NN, NN, 4), 64, 0, stream>>>(txt, img, ws);
    pairs_kernel<<<36, 256, 0, stream>>>(ws);
    lse_kernel<<<NBLK, 256, 0, stream>>>(ws, (float*)d_out);
}

// Round 4
// 99.340 us; speedup vs baseline: 2.1947x; 1.4117x over previous
//
#include <hip/hip_runtime.h>
#include <math.h>

#define NN 96
#define DD 512
#define PP 9120          // NN*(NN-1)
#define EPSF 1e-8f
#define INV_TEMP 100.0f
#define LOG2E 1.4426950408889634f
#define RT 8             // tasks (rows/cols of mma) per lse block
#define NTASK (2*PP)     // 18240
#define NBLK (NTASK/RT)  // 2280
#define CBASE (PP/RT)    // 1140: first block index handling column tasks

// ws float-offset layout
#define OFF_PART  0        // 6 partial grams [zz][9216], zz = z*2+kslice; z=0:G z=1:Gt z=2:Gm
#define OFF_G     55296    // G  = txt*img^T   [96*96]
#define OFF_GT    64512    // GT = G^T         [96*96]
#define OFF_WT    73728    // wt[k][l] = 1/(||t_k-t_l||+eps), diag 0
#define OFF_WM    82944
#define OFF_WST   92160    // wt * log2e
#define OFF_WSM   101376   // wm * log2e
#define OFF_DIAG  110592   // diag[p]
#define OFF_WMAX  119712   // [0]=max wt, [1]=max wm (uint bits)
#define OFF_BSUM  119720   // per-lse-block partial sums [NBLK]

__device__ __forceinline__ void decomp(unsigned p, int& i, int& j) {
    unsigned ii = p / 95u;
    unsigned r  = p - ii * 95u;
    i = (int)ii;
    j = (int)(r + (r >= ii ? 1u : 0u));
}

// Split-K tiled gram: block computes 16x16 tile over a 256-dim K slice.
// grid (6,6,6): x=a-tile, y=b-tile, z=zz (gram*2+kslice)
__global__ __launch_bounds__(256) void gram_kernel(const float* __restrict__ txt,
                                                   const float* __restrict__ img,
                                                   float* __restrict__ ws) {
    __shared__ float4 Al[16][65];   // pitch 65 float4 = 260 floats (16B-aligned rows)
    __shared__ float4 Bl[16][65];
    int zz = blockIdx.z;
    int z = zz >> 1, ks = zz & 1;
    int a0 = blockIdx.x * 16, b0 = blockIdx.y * 16;
    const float* X = (z == 2) ? img : txt;
    const float* Y = (z == 0) ? img : ((z == 1) ? txt : img);
    const float4* Xp = (const float4*)X;     // row stride 128 float4
    const float4* Yp = (const float4*)Y;
    int tid = threadIdx.x;
    int r = tid >> 6, c = tid & 63;
    int kbase = ks * 64;                      // float4 offset of K slice
    #pragma unroll
    for (int rep = 0; rep < 4; ++rep) {
        int row = rep * 4 + r;
        Al[row][c] = Xp[(a0 + row) * 128 + kbase + c];
        Bl[row][c] = Yp[(b0 + row) * 128 + kbase + c];
    }
    __syncthreads();
    int al = tid >> 4, bl = tid & 15;
    float acc = 0.f;
    #pragma unroll 8
    for (int kk = 0; kk < 64; ++kk) {
        float4 av = Al[al][kk];
        float4 bv = Bl[bl][kk];
        acc += av.x*bv.x + av.y*bv.y + av.z*bv.z + av.w*bv.w;
    }
    ws[OFF_PART + zz * (NN*NN) + (a0 + al) * NN + (b0 + bl)] = acc;
}

// per (k,l): combine K-slice partials, build G/GT, inverse-norm grids, diag, Wmax
__global__ void pairs_kernel(float* __restrict__ ws) {
    int t = blockIdx.x * 256 + threadIdx.x;
    if (t >= NN * NN) return;
    int k = t / NN, l = t - k * NN;
    const float* P = ws + OFF_PART;
    #define RD(z, x) (P[(2*(z)) * (NN*NN) + (x)] + P[(2*(z)+1) * (NN*NN) + (x)])
    float gkl = RD(0, k*NN + l);
    float glk = RD(0, l*NN + k);
    ws[OFF_G  + t] = gkl;
    ws[OFF_GT + t] = glk;
    float wtv = 0.f, wmv = 0.f;
    if (k != l) {
        float nt2 = RD(1, k*NN+k) - 2.f*RD(1, k*NN+l) + RD(1, l*NN+l);
        float nm2 = RD(2, k*NN+k) - 2.f*RD(2, k*NN+l) + RD(2, l*NN+l);
        wtv = 1.f / (sqrtf(fmaxf(nt2, 0.f)) + EPSF);
        wmv = 1.f / (sqrtf(fmaxf(nm2, 0.f)) + EPSF);
        atomicMax((unsigned int*)(ws + OFF_WMAX) + 0, __float_as_uint(wtv));
        atomicMax((unsigned int*)(ws + OFF_WMAX) + 1, __float_as_uint(wmv));
        int p = k * 95 + l - (l > k ? 1 : 0);
        float gkk = RD(0, k*NN+k), gll = RD(0, l*NN+l);
        ws[OFF_DIAG + p] = INV_TEMP * wtv * wmv * (gkk - gkl - glk + gll);
    }
    #undef RD
    ws[OFF_WT  + t] = wtv;
    ws[OFF_WM  + t] = wmv;
    ws[OFF_WST + t] = wtv * LOG2E;
    ws[OFF_WSM + t] = wmv * LOG2E;
}

// One block = RT consecutive tasks (all-row or all-col). Sweep the 96x96 (k,l)
// grid (diag w=0 -> contributes exp(-M) each, removed exactly). Shift
// M_r = Wmax*(amax_r - amin_r) >= true row max: exact LSE, no max pass.
__global__ __launch_bounds__(256) void lse_kernel(float* __restrict__ ws) {
    __shared__ float A[RT * NN];
    __shared__ float M2s[RT];     // M * log2e
    __shared__ float Ms[RT];      // M
    __shared__ float wred[4][RT];
    __shared__ float cred[RT];

    int tid = threadIdx.x, lane = tid & 63, wv = tid >> 6;
    int b = blockIdx.x;
    bool is_col = (b >= CBASE);
    const float* Mat    = ws + (is_col ? OFF_GT  : OFF_G);
    const float* wself  = ws + (is_col ? OFF_WM  : OFF_WT);
    const float* wsweep = ws + (is_col ? OFF_WST : OFF_WSM);
    float Wmax = __uint_as_float(((const unsigned int*)(ws + OFF_WMAX))[is_col ? 0 : 1]);
    int base = (b - (is_col ? CBASE : 0)) * RT;

    // wave wv builds rows 2wv, 2wv+1 of A
    #pragma unroll
    for (int q = 0; q < 2; ++q) {
        int rr = 2 * wv + q;
        int i, j; decomp((unsigned)(base + rr), i, j);
        float s = INV_TEMP * wself[i * NN + j];
        const float* Mi = Mat + i * NN;
        const float* Mj = Mat + j * NN;
        float v0 = s * (Mi[lane] - Mj[lane]);
        A[rr * NN + lane] = v0;
        float vmax = v0, vmin = v0;
        if (lane < 32) {
            float v1 = s * (Mi[64 + lane] - Mj[64 + lane]);
            A[rr * NN + 64 + lane] = v1;
            vmax = fmaxf(vmax, v1); vmin = fminf(vmin, v1);
        }
        #pragma unroll
        for (int off = 32; off > 0; off >>= 1) {
            vmax = fmaxf(vmax, __shfl_xor(vmax, off, 64));
            vmin = fminf(vmin, __shfl_xor(vmin, off, 64));
        }
        if (lane == 0) {
            float M = Wmax * (vmax - vmin);
            Ms[rr] = M;
            M2s[rr] = M * LOG2E;
        }
    }
    __syncthreads();

    int l1 = (lane < 32) ? (64 + lane) : (lane - 32);
    float M2[RT], aL0[RT], aL1[RT], aL2[RT], S[RT];
    #pragma unroll
    for (int r = 0; r < RT; ++r) {
        M2[r] = M2s[r];
        aL0[r] = A[r * NN + lane];
        aL1[r] = A[r * NN + l1];
        aL2[r] = A[r * NN + lane + 32];
        S[r] = 0.f;
    }

    // wave wv handles k-pairs idx in {wv, wv+4, ...}: (k0,k1)=(2idx,2idx+1)
    //  step0: (k0, lane)  step1: lane<32 ? (k0,64+lane) : (k1,lane-32)  step2: (k1, 32+lane)
    for (int idx = wv; idx < 48; idx += 4) {
        int k0 = 2 * idx, k1 = k0 + 1;
        float w0 = wsweep[k0 * NN + lane];
        float w1 = wsweep[(lane < 32 ? k0 : k1) * NN + l1];
        float w2 = wsweep[k1 * NN + lane + 32];
        #pragma unroll
        for (int r = 0; r < RT; ++r) {
            float2 ak = *(const float2*)&A[r * NN + k0];   // k0 even -> 8B aligned
            float aksel = (lane < 32) ? ak.x : ak.y;
            S[r] += __builtin_amdgcn_exp2f(w0 * (ak.x  - aL0[r]) - M2[r])
                  + __builtin_amdgcn_exp2f(w1 * (aksel - aL1[r]) - M2[r])
                  + __builtin_amdgcn_exp2f(w2 * (ak.y  - aL2[r]) - M2[r]);
        }
    }

    #pragma unroll
    for (int off = 32; off > 0; off >>= 1) {
        #pragma unroll
        for (int r = 0; r < RT; ++r) S[r] += __shfl_xor(S[r], off, 64);
    }
    if (lane == 0) {
        #pragma unroll
        for (int r = 0; r < RT; ++r) wred[wv][r] = S[r];
    }
    __syncthreads();

    if (tid < RT) {
        int r = tid;
        float tot = wred[0][r] + wred[1][r] + wred[2][r] + wred[3][r];
        tot -= 96.f * __builtin_amdgcn_exp2f(-M2s[r]);     // remove w=0 diagonal slots
        cred[r] = Ms[r] + logf(tot) - ws[OFF_DIAG + base + r];
    }
    __syncthreads();
    if (tid == 0) {
        float c = 0.f;
        #pragma unroll
        for (int r = 0; r < RT; ++r) c += cred[r];
        ws[OFF_BSUM + b] = c;     // no global atomic: per-block partial
    }
}

__global__ void final_kernel(const float* __restrict__ ws, float* __restrict__ out) {
    __shared__ float red[256];
    int tid = threadIdx.x;
    float s = 0.f;
    for (int i = tid; i < NBLK; i += 256)
        s += ws[OFF_BSUM + i];
    red[tid] = s; __syncthreads();
    for (int t = 128; t > 0; t >>= 1) {
        if (tid < t) red[tid] += red[tid + t];
        __syncthreads();
    }
    if (tid == 0) out[0] = red[0] * (1.0f / (float)NTASK);
}

extern "C" void kernel_launch(void* const* d_in, const int* in_sizes, int n_in,
                              void* d_out, int out_size, void* d_ws, size_t ws_size,
                              hipStream_t stream) {
    const float* txt = (const float*)d_in[0];
    const float* img = (const float*)d_in[1];
    float* ws = (float*)d_ws;

    (void)hipMemsetAsync(ws + OFF_WMAX, 0, 2 * sizeof(float), stream);
    gram_kernel<<<dim3(6, 6, 6), 256, 0, stream>>>(txt, img, ws);
    pairs_kernel<<<36, 256, 0, stream>>>(ws);
    lse_kernel<<<NBLK, 256, 0, stream>>>(ws);
    final_kernel<<<1, 256, 0, stream>>>(ws, (float*)d_out);
}